// Round 10
// baseline (283.710 us; speedup 1.0000x reference)
//
#include <hip/hip_runtime.h>
#include <hip/hip_bf16.h>

// Problem constants (B=4, N=4096, D=1024, H=16, hd=64, G=512, sigma=3)
#define NPOS 4096
#define DIM  1024
#define GSZ  512

#define GAS __attribute__((address_space(1)))
#define LAS __attribute__((address_space(3)))

typedef __attribute__((ext_vector_type(8))) short bf16x8;   // 8 bf16 (4 VGPRs)
typedef __attribute__((ext_vector_type(4))) float f32x4;

__device__ __forceinline__ void async_load16(const void* g, void* l) {
  __builtin_amdgcn_global_load_lds((const GAS void*)g, (LAS void*)l, 16, 0, 0);
}

// Bit-exact replica of np: (arange(N,f32)/4095)*511 then trunc-to-int32.
__device__ __forceinline__ int fidx_of(int n) {
  return (int)(((float)n / 4095.0f) * 511.0f);
}

__device__ __forceinline__ float bf2f(unsigned short s) {
  union { unsigned u; float f; } v; v.u = ((unsigned)s) << 16; return v.f;
}

// RNE f32->bf16 x8 pack (bit-identical to the old cast_all path)
__device__ __forceinline__ bf16x8 pack8(float4 lo, float4 hi) {
  bf16x8 r;
  union { __hip_bfloat16 b; short s; } u;
  u.b = __float2bfloat16(lo.x); r[0] = u.s;
  u.b = __float2bfloat16(lo.y); r[1] = u.s;
  u.b = __float2bfloat16(lo.z); r[2] = u.s;
  u.b = __float2bfloat16(lo.w); r[3] = u.s;
  u.b = __float2bfloat16(hi.x); r[4] = u.s;
  u.b = __float2bfloat16(hi.y); r[5] = u.s;
  u.b = __float2bfloat16(hi.z); r[6] = u.s;
  u.b = __float2bfloat16(hi.w); r[7] = u.s;
  return r;
}

// exact [i0,i1) row-range of bin g under fidx_of
// NOTE: bins are 8 or 9 rows EXCEPT bin 511 which has exactly 1 row (n=4095).
__device__ __forceinline__ void bin_range(int g, int& i0, int& i1) {
  i0 = (g * 4095 + 510) / 511;
  while (i0 > 0 && fidx_of(i0 - 1) >= g) --i0;
  while (i0 < NPOS && fidx_of(i0) < g) ++i0;
  if (g == GSZ - 1) { i1 = NPOS; return; }
  i1 = ((g + 1) * 4095 + 510) / 511;
  while (i1 > 0 && fidx_of(i1 - 1) >= g + 1) --i1;
  while (i1 < NPOS && fidx_of(i1) < g + 1) ++i1;
}

// ---------------- weight casts only (x-cast now fused into gemm_kv) ----------------
// blocks [0,1024): k_w ; [1024,2048): v_w ; [2048,3072): out_w
__global__ __launch_bounds__(256) void cast_all(
    const float* __restrict__ kw, const float* __restrict__ vw,
    const float* __restrict__ ow,
    __hip_bfloat16* __restrict__ kvwb, __hip_bfloat16* __restrict__ outwb) {
  int blk = blockIdx.x;
  const float* src; __hip_bfloat16* dst; int off;
  if (blk < 1024)      { src = kw; dst = kvwb;            off = blk; }
  else if (blk < 2048) { src = vw; dst = kvwb + 1048576;  off = blk - 1024; }
  else                 { src = ow; dst = outwb;           off = blk - 2048; }
  int i = (off * 256 + threadIdx.x) * 4;
  float4 f = *(const float4*)(src + i);
  ushort4 o;
  __hip_bfloat16 t;
  t = __float2bfloat16(f.x); o.x = *(unsigned short*)&t;
  t = __float2bfloat16(f.y); o.y = *(unsigned short*)&t;
  t = __float2bfloat16(f.z); o.z = *(unsigned short*)&t;
  t = __float2bfloat16(f.w); o.w = *(unsigned short*)&t;
  *(ushort4*)(dst + i) = o;
}

// ---------------- KV GEMM: A = x (f32, staged direct + in-reg bf16 cvt) ----------------
// C = bf16(x) @ B^T + bias, 128x128 tile, BK=32. A staged as f32 into LDS via
// global_load_lds with XOR chunk swizzle (chunk ^= row&7) so the 16-lane
// fragment reads spread over all 32 banks (2-way = free). The swizzle is applied
// on the GLOBAL source address (keeps 128B/row coalescing + the wave-uniform
// base + lane*16 DMA constraint) and inverted on the LDS read.
__global__ __launch_bounds__(256) void gemm_kv(
    const float* __restrict__ X,
    const __hip_bfloat16* __restrict__ B,
    const float* __restrict__ bias0, const float* __restrict__ bias1,
    __hip_bfloat16* __restrict__ C, int N) {
  const int K = 1024;
  __shared__ __align__(16) float Asf[128 * 32];            // 16 KB
  __shared__ __align__(16) __hip_bfloat16 Bs[128 * 32];    // 8 KB
  const int tid = threadIdx.x;
  const int bm = blockIdx.x * 128, bn = blockIdx.y * 128;

  // A staging: idx = issue*256+tid -> row = idx>>3 (= issue*32 + tid>>3), pos j = tid&7.
  // LDS pos j of row holds global chunk c = j ^ (row&7); row&7 == (tid>>3)&7 for all issues.
  const int swz = (tid & 7) ^ ((tid >> 3) & 7);
  const float* xp0 = X + (size_t)(bm + (tid >> 3)) * K + swz * 4;
  float* asf0 = Asf + tid * 4;                              // dest: base + tid*16B

  // B staging (bf16, unchanged geometry)
  const int srow = tid >> 2;          // 0..63
  const int scol = (tid & 3) * 8;     // 0,8,16,24
  const __hip_bfloat16* bp0 = B + (size_t)(bn + srow) * K + scol;
  const __hip_bfloat16* bp1 = B + (size_t)(bn + srow + 64) * K + scol;
  __hip_bfloat16* bs0 = &Bs[srow * 32 + scol];
  __hip_bfloat16* bs1 = &Bs[(srow + 64) * 32 + scol];

  const int wave = tid >> 6, lane = tid & 63;
  const int wm = (wave >> 1) * 64, wn = (wave & 1) * 64;
  const int m16 = lane & 15, quad = lane >> 4;
  const int clane = (2 * quad) ^ (m16 & 7);   // lo-chunk LDS position (row&7 == m16&7)

  f32x4 acc[4][4];
#pragma unroll
  for (int i = 0; i < 4; i++)
#pragma unroll
    for (int j = 0; j < 4; j++) acc[i][j] = (f32x4)0.f;

  for (int k0 = 0; k0 < K; k0 += 32) {
    async_load16(xp0 + k0, asf0);
    async_load16(xp0 + 32 * K + k0, asf0 + 1024);
    async_load16(xp0 + 64 * K + k0, asf0 + 2048);
    async_load16(xp0 + 96 * K + k0, asf0 + 3072);
    async_load16(bp0 + k0, bs0);
    async_load16(bp1 + k0, bs1);
    __syncthreads();
    bf16x8 af[4], bfr[4];
    const float4* a4 = (const float4*)Asf;
#pragma unroll
    for (int mt = 0; mt < 4; mt++) {
      int row = wm + mt * 16 + m16;
      float4 lo = a4[row * 8 + clane];
      float4 hi = a4[row * 8 + (clane ^ 1)];
      af[mt] = pack8(lo, hi);
    }
#pragma unroll
    for (int nt = 0; nt < 4; nt++)
      bfr[nt] = *(const bf16x8*)&Bs[(wn + nt * 16 + m16) * 32 + quad * 8];
#pragma unroll
    for (int mt = 0; mt < 4; mt++)
#pragma unroll
      for (int nt = 0; nt < 4; nt++)
        acc[mt][nt] = __builtin_amdgcn_mfma_f32_16x16x32_bf16(af[mt], bfr[nt], acc[mt][nt], 0, 0, 0);
    __syncthreads();
  }

  // epilogue: C/D layout col=lane&15, row=quad*4+reg (m89/m91-verified)
#pragma unroll
  for (int mt = 0; mt < 4; mt++) {
#pragma unroll
    for (int nt = 0; nt < 4; nt++) {
      int col = bn + wn + nt * 16 + m16;
      float bv = (col < 1024) ? bias0[col] : bias1[col - 1024];
#pragma unroll
      for (int r = 0; r < 4; r++) {
        int row = bm + wm + mt * 16 + quad * 4 + r;
        C[(size_t)row * N + col] = __float2bfloat16(acc[mt][nt][r] + bv);
      }
    }
  }
}

// ---------------- dedup output GEMM: outc = conv @ outw^T + bias (f32) ----------------
// M=2048, N=1024, K=1024. 64x64 tiles -> grid (32,16) = 512 blocks (2/CU). FROZEN (r7).
__global__ __launch_bounds__(256) void gemm_outc(
    const __hip_bfloat16* __restrict__ A,
    const __hip_bfloat16* __restrict__ B,
    const float* __restrict__ bias,
    float* __restrict__ C) {
  const int K = 1024;
  __shared__ __align__(16) __hip_bfloat16 As[64 * 32];
  __shared__ __align__(16) __hip_bfloat16 Bs[64 * 32];
  const int tid = threadIdx.x;
  const int bm = blockIdx.x * 64, bn = blockIdx.y * 64;

  const int srow = tid >> 2;          // 0..63
  const int scol = (tid & 3) * 8;     // 0,8,16,24
  const __hip_bfloat16* ap = A + (size_t)(bm + srow) * K + scol;
  const __hip_bfloat16* bp = B + (size_t)(bn + srow) * K + scol;
  __hip_bfloat16* as = &As[srow * 32 + scol];   // = LDS byte addr tid*16
  __hip_bfloat16* bs = &Bs[srow * 32 + scol];

  const int wave = tid >> 6, lane = tid & 63;
  const int wm = (wave >> 1) * 32, wn = (wave & 1) * 32;   // 2x2 waves, 32x32 each
  const int m16 = lane & 15, quad = lane >> 4;

  f32x4 acc[2][2];
#pragma unroll
  for (int i = 0; i < 2; i++)
#pragma unroll
    for (int j = 0; j < 2; j++) acc[i][j] = (f32x4)0.f;

  for (int k0 = 0; k0 < K; k0 += 32) {
    async_load16(ap + k0, as);
    async_load16(bp + k0, bs);
    __syncthreads();
    bf16x8 af[2], bfr[2];
#pragma unroll
    for (int mt = 0; mt < 2; mt++)
      af[mt] = *(const bf16x8*)&As[(wm + mt * 16 + m16) * 32 + quad * 8];
#pragma unroll
    for (int nt = 0; nt < 2; nt++)
      bfr[nt] = *(const bf16x8*)&Bs[(wn + nt * 16 + m16) * 32 + quad * 8];
#pragma unroll
    for (int mt = 0; mt < 2; mt++)
#pragma unroll
      for (int nt = 0; nt < 2; nt++)
        acc[mt][nt] = __builtin_amdgcn_mfma_f32_16x16x32_bf16(af[mt], bfr[nt], acc[mt][nt], 0, 0, 0);
    __syncthreads();
  }

#pragma unroll
  for (int mt = 0; mt < 2; mt++) {
#pragma unroll
    for (int nt = 0; nt < 2; nt++) {
      int col = bn + wn + nt * 16 + m16;
      float bv = bias[col];
#pragma unroll
      for (int r = 0; r < 4; r++) {
        int row = bm + wm + mt * 16 + quad * 4 + r;
        C[(size_t)row * 1024 + col] = acc[mt][nt][r] + bv;
      }
    }
  }
}

// ---------------- gather: d_out[b,n,:] = outc[b*512+fidx(n),:], float4 stream ----------------
__global__ __launch_bounds__(256) void gather_out_kernel(
    const float* __restrict__ outc, float* __restrict__ out) {
  const int row = blockIdx.x;            // b*4096 + n
  const int b = row >> 12, n = row & (NPOS - 1);
  const int g = fidx_of(n);
  const float4* src = (const float4*)(outc + ((size_t)(b * GSZ) + g) * DIM);
  float4* dst = (float4*)(out + (size_t)row * DIM);
  dst[threadIdx.x] = src[threadIdx.x];
}

// ---------------- field: segment-sum of v * ||k|| into G bins (r9, FROZEN) ----------------
__global__ __launch_bounds__(256) void wv_field_kernel(
    const __hip_bfloat16* __restrict__ KV, float* __restrict__ field) {
  const int b = blockIdx.x, g = blockIdx.y;
  int i0, i1;
  bin_range(g, i0, i1);
  int cnt = i1 - i0;                 // 1, 8 or 9
  if (cnt > 9) cnt = 9;
  __shared__ float km[9][16];        // [row][head]
  const int tid = threadIdx.x;
  if (tid < 144) {                   // phase 1: ||k|| per (row, head); zero-fill r>=cnt
    int r = tid >> 4, h = tid & 15;
    float s = 0.f;
    if (r < cnt) {
      const unsigned short* kp = (const unsigned short*)KV + (size_t)(b * NPOS + i0 + r) * 2048 + h * 64;
#pragma unroll
      for (int e = 0; e < 64; e += 8) {
        bf16x8 v = *(const bf16x8*)(kp + e);
#pragma unroll
        for (int q = 0; q < 8; ++q) { float f = bf2f((unsigned short)v[q]); s += f * f; }
      }
      s = sqrtf(s);
    }
    km[r][h] = s;                    // 0 for padding rows
  }
  __syncthreads();
  const int c0 = tid * 4, h = tid >> 4;   // h = c0>>6
  const unsigned short* vbase = (const unsigned short*)KV + (size_t)(b * NPOS + i0) * 2048 + 1024 + c0;
  ushort4 vv[8];
  float ww[8];
#pragma unroll
  for (int j = 0; j < 8; ++j) {
    int jc = (j < cnt) ? j : 0;           // clamp: valid row, weight 0 below
    vv[j] = *(const ushort4*)(vbase + (size_t)jc * 2048);
    ww[j] = (j < cnt) ? km[j][h] : 0.f;
  }
  float a0 = 0.f, a1 = 0.f, a2 = 0.f, a3 = 0.f;
#pragma unroll
  for (int j = 0; j < 8; ++j) {
    a0 += ww[j] * bf2f(vv[j].x); a1 += ww[j] * bf2f(vv[j].y);
    a2 += ww[j] * bf2f(vv[j].z); a3 += ww[j] * bf2f(vv[j].w);
  }
  if (cnt == 9) {
    ushort4 v8 = *(const ushort4*)(vbase + (size_t)8 * 2048);
    float w8 = km[8][h];
    a0 += w8 * bf2f(v8.x); a1 += w8 * bf2f(v8.y);
    a2 += w8 * bf2f(v8.z); a3 += w8 * bf2f(v8.w);
  }
  *(float4*)(field + ((size_t)(b * GSZ + g)) * DIM + c0) = make_float4(a0, a1, a2, a3);
}

// ---------------- causal conv as EMA recurrence, LDS-staged (r9, FROZEN) ----------------
__global__ __launch_bounds__(256) void conv_ema_kernel(
    const float* __restrict__ field, __hip_bfloat16* __restrict__ convb) {
  const int b = blockIdx.x, h = blockIdx.y, n0 = blockIdx.z * 64;
  __shared__ float slab[128 * 64];
  const int tid = threadIdx.x;
  const float* fb = field + (size_t)b * GSZ * DIM + h * 64;
  for (int i = tid; i < 128 * 16; i += 256) {         // float4 loads, 8/thread
    int row = i >> 4, c4 = i & 15;
    int gg = (n0 + 257 + row) & (GSZ - 1);
    *(float4*)&slab[row * 64 + c4 * 4] = *(const float4*)(fb + (size_t)gg * DIM + c4 * 4);
  }
  __syncthreads();
  const float a = 0.71653131057378927f;   // exp(-1/3)
  const float w1 = 1.0f - a;
  const int c = tid & 63, sub = tid >> 6;
  const int e0 = sub * 16;                // emit slab range [e0, e0+16)
  float acc = 0.f;
#pragma unroll 4
  for (int t = e0 + 79; t >= e0 + 16; --t)            // 64-step warm-up (a^64 ~ 5e-10)
    acc = w1 * slab[t * 64 + c] + a * acc;
#pragma unroll
  for (int t = e0 + 15; t >= e0; --t) {
    acc = w1 * slab[t * 64 + c] + a * acc;
    convb[((size_t)(b * GSZ) + n0 + t) * DIM + h * 64 + c] = __float2bfloat16(acc);
  }
}

extern "C" void kernel_launch(void* const* d_in, const int* in_sizes, int n_in,
                              void* d_out, int out_size, void* d_ws, size_t ws_size,
                              hipStream_t stream) {
  (void)in_sizes; (void)n_in; (void)out_size; (void)ws_size;
  const float* x     = (const float*)d_in[0];
  // d_in[1]=q_w, d_in[2]=q_b: dead in the reference — skipped.
  const float* k_w   = (const float*)d_in[3];
  const float* k_b   = (const float*)d_in[4];
  const float* v_w   = (const float*)d_in[5];
  const float* v_b   = (const float*)d_in[6];
  const float* out_w = (const float*)d_in[7];
  const float* out_b = (const float*)d_in[8];

  char* p = (char*)d_ws;
  float*          outc  = (float*)p;          p += (size_t)2048 * 1024 * 4;   // 8 MB
  __hip_bfloat16* kvwb  = (__hip_bfloat16*)p; p += (size_t)2048 * 1024 * 2;   // 4 MB
  __hip_bfloat16* outwb = (__hip_bfloat16*)p; p += (size_t)1024 * 1024 * 2;   // 2 MB
  __hip_bfloat16* KV    = (__hip_bfloat16*)p; p += (size_t)16384 * 2048 * 2;  // 64 MB
  float*          field = (float*)p;          p += (size_t)4 * 512 * 1024 * 4;// 8 MB
  __hip_bfloat16* convb = (__hip_bfloat16*)p;                                 // 4 MB

  cast_all<<<3072, 256, 0, stream>>>(k_w, v_w, out_w, kvwb, outwb);

  // fused K+V projection with in-kernel x cast: (16384x1024 f32) @ (2048x1024)^T -> KV bf16
  gemm_kv<<<dim3(128, 16), 256, 0, stream>>>(x, kvwb, k_b, v_b, KV, 2048);

  wv_field_kernel<<<dim3(4, 512), 256, 0, stream>>>(KV, field);
  conv_ema_kernel<<<dim3(4, 16, 8), 256, 0, stream>>>(field, convb);

  // dedup'd output GEMM (2048 distinct rows, 512 blocks) then streaming gather
  gemm_outc<<<dim3(32, 16), 256, 0, stream>>>(convb, outwb, out_b, outc);
  gather_out_kernel<<<16384, 256, 0, stream>>>(outc, (float*)d_out);
}

// Round 11
// 275.177 us; speedup vs baseline: 1.0310x; 1.0310x over previous
//
#include <hip/hip_runtime.h>
#include <hip/hip_bf16.h>

// Problem constants (B=4, N=4096, D=1024, H=16, hd=64, G=512, sigma=3)
#define NPOS 4096
#define DIM  1024
#define GSZ  512

#define GAS __attribute__((address_space(1)))
#define LAS __attribute__((address_space(3)))

typedef __attribute__((ext_vector_type(8))) short bf16x8;   // 8 bf16 (4 VGPRs)
typedef __attribute__((ext_vector_type(4))) float f32x4;

__device__ __forceinline__ void async_load16(const void* g, void* l) {
  __builtin_amdgcn_global_load_lds((const GAS void*)g, (LAS void*)l, 16, 0, 0);
}

// Bit-exact replica of np: (arange(N,f32)/4095)*511 then trunc-to-int32.
__device__ __forceinline__ int fidx_of(int n) {
  return (int)(((float)n / 4095.0f) * 511.0f);
}

__device__ __forceinline__ float bf2f(unsigned short s) {
  union { unsigned u; float f; } v; v.u = ((unsigned)s) << 16; return v.f;
}

// exact [i0,i1) row-range of bin g under fidx_of
// NOTE: bins are 8 or 9 rows EXCEPT bin 511 which has exactly 1 row (n=4095).
__device__ __forceinline__ void bin_range(int g, int& i0, int& i1) {
  i0 = (g * 4095 + 510) / 511;
  while (i0 > 0 && fidx_of(i0 - 1) >= g) --i0;
  while (i0 < NPOS && fidx_of(i0) < g) ++i0;
  if (g == GSZ - 1) { i1 = NPOS; return; }
  i1 = ((g + 1) * 4095 + 510) / 511;
  while (i1 > 0 && fidx_of(i1 - 1) >= g + 1) --i1;
  while (i1 < NPOS && fidx_of(i1) < g + 1) ++i1;
}

// ---------------- all f32->bf16 casts in one launch (r9 config) ----------------
// blocks [0,16384): x ; [16384,17408): k_w ; [17408,18432): v_w ; [18432,19456): out_w
__global__ __launch_bounds__(256) void cast_all(
    const float* __restrict__ x, const float* __restrict__ kw,
    const float* __restrict__ vw, const float* __restrict__ ow,
    __hip_bfloat16* __restrict__ xb, __hip_bfloat16* __restrict__ kvwb,
    __hip_bfloat16* __restrict__ outwb) {
  int blk = blockIdx.x;
  const float* src; __hip_bfloat16* dst; int off;
  if (blk < 16384)      { src = x;  dst = xb;              off = blk; }
  else if (blk < 17408) { src = kw; dst = kvwb;            off = blk - 16384; }
  else if (blk < 18432) { src = vw; dst = kvwb + 1048576;  off = blk - 17408; }
  else                  { src = ow; dst = outwb;           off = blk - 18432; }
  int i = (off * 256 + threadIdx.x) * 4;
  float4 f = *(const float4*)(src + i);
  ushort4 o;
  __hip_bfloat16 t;
  t = __float2bfloat16(f.x); o.x = *(unsigned short*)&t;
  t = __float2bfloat16(f.y); o.y = *(unsigned short*)&t;
  t = __float2bfloat16(f.z); o.z = *(unsigned short*)&t;
  t = __float2bfloat16(f.w); o.w = *(unsigned short*)&t;
  *(ushort4*)(dst + i) = o;
}

// ---------------- 128x128-tile bf16 MFMA GEMM, BK=64 (two BK=32 half-buffers) ----------------
// A: M x K row-major; B: N x K row-major; bias per column (cols<1024 -> bias0).
// Each half uses the proven m97 LDS geometry; barriers per K-loop halved (62 -> 32).
__global__ __launch_bounds__(256) void gemm_bt(
    const __hip_bfloat16* __restrict__ A,
    const __hip_bfloat16* __restrict__ B,
    const float* __restrict__ bias0, const float* __restrict__ bias1,
    __hip_bfloat16* __restrict__ C, int N) {
  const int K = 1024;
  __shared__ __align__(16) __hip_bfloat16 As[2][128 * 32];
  __shared__ __align__(16) __hip_bfloat16 Bs[2][128 * 32];
  const int tid = threadIdx.x;
  const int bm = blockIdx.x * 128, bn = blockIdx.y * 128;

  const int srow = tid >> 2;          // 0..63
  const int scol = (tid & 3) * 8;     // 0,8,16,24
  const __hip_bfloat16* ap0 = A + (size_t)(bm + srow) * K + scol;
  const __hip_bfloat16* ap1 = A + (size_t)(bm + srow + 64) * K + scol;
  const __hip_bfloat16* bp0 = B + (size_t)(bn + srow) * K + scol;
  const __hip_bfloat16* bp1 = B + (size_t)(bn + srow + 64) * K + scol;
  const int soff = srow * 32 + scol;  // lane-ordered: tid*16B within each half

  const int wave = tid >> 6, lane = tid & 63;
  const int wm = (wave >> 1) * 64, wn = (wave & 1) * 64;
  const int m16 = lane & 15, quad = lane >> 4;

  f32x4 acc[4][4];
#pragma unroll
  for (int i = 0; i < 4; i++)
#pragma unroll
    for (int j = 0; j < 4; j++) acc[i][j] = (f32x4)0.f;

  for (int k0 = 0; k0 < K; k0 += 64) {
    // stage both 32-wide halves, then one barrier pair for 32 MFMAs
    async_load16(ap0 + k0, &As[0][soff]);
    async_load16(ap1 + k0, &As[0][soff + 64 * 32]);
    async_load16(bp0 + k0, &Bs[0][soff]);
    async_load16(bp1 + k0, &Bs[0][soff + 64 * 32]);
    async_load16(ap0 + k0 + 32, &As[1][soff]);
    async_load16(ap1 + k0 + 32, &As[1][soff + 64 * 32]);
    async_load16(bp0 + k0 + 32, &Bs[1][soff]);
    async_load16(bp1 + k0 + 32, &Bs[1][soff + 64 * 32]);
    __syncthreads();
#pragma unroll
    for (int h = 0; h < 2; h++) {
      bf16x8 af[4], bfr[4];
#pragma unroll
      for (int mt = 0; mt < 4; mt++)
        af[mt] = *(const bf16x8*)&As[h][(wm + mt * 16 + m16) * 32 + quad * 8];
#pragma unroll
      for (int nt = 0; nt < 4; nt++)
        bfr[nt] = *(const bf16x8*)&Bs[h][(wn + nt * 16 + m16) * 32 + quad * 8];
#pragma unroll
      for (int mt = 0; mt < 4; mt++)
#pragma unroll
        for (int nt = 0; nt < 4; nt++)
          acc[mt][nt] = __builtin_amdgcn_mfma_f32_16x16x32_bf16(af[mt], bfr[nt], acc[mt][nt], 0, 0, 0);
    }
    __syncthreads();
  }

  // epilogue: C/D layout col=lane&15, row=quad*4+reg (m89/m91-verified)
#pragma unroll
  for (int mt = 0; mt < 4; mt++) {
#pragma unroll
    for (int nt = 0; nt < 4; nt++) {
      int col = bn + wn + nt * 16 + m16;
      float bv = (col < 1024) ? bias0[col] : bias1[col - 1024];
#pragma unroll
      for (int r = 0; r < 4; r++) {
        int row = bm + wm + mt * 16 + quad * 4 + r;
        C[(size_t)row * N + col] = __float2bfloat16(acc[mt][nt][r] + bv);
      }
    }
  }
}

// ---------------- dedup output GEMM: outc = conv @ outw^T + bias (f32) ----------------
// M=2048, N=1024, K=1024. 64x64 tiles -> grid (32,16) = 512 blocks (2/CU). FROZEN (r7).
__global__ __launch_bounds__(256) void gemm_outc(
    const __hip_bfloat16* __restrict__ A,
    const __hip_bfloat16* __restrict__ B,
    const float* __restrict__ bias,
    float* __restrict__ C) {
  const int K = 1024;
  __shared__ __align__(16) __hip_bfloat16 As[64 * 32];
  __shared__ __align__(16) __hip_bfloat16 Bs[64 * 32];
  const int tid = threadIdx.x;
  const int bm = blockIdx.x * 64, bn = blockIdx.y * 64;

  const int srow = tid >> 2;          // 0..63
  const int scol = (tid & 3) * 8;     // 0,8,16,24
  const __hip_bfloat16* ap = A + (size_t)(bm + srow) * K + scol;
  const __hip_bfloat16* bp = B + (size_t)(bn + srow) * K + scol;
  __hip_bfloat16* as = &As[srow * 32 + scol];   // = LDS byte addr tid*16
  __hip_bfloat16* bs = &Bs[srow * 32 + scol];

  const int wave = tid >> 6, lane = tid & 63;
  const int wm = (wave >> 1) * 32, wn = (wave & 1) * 32;   // 2x2 waves, 32x32 each
  const int m16 = lane & 15, quad = lane >> 4;

  f32x4 acc[2][2];
#pragma unroll
  for (int i = 0; i < 2; i++)
#pragma unroll
    for (int j = 0; j < 2; j++) acc[i][j] = (f32x4)0.f;

  for (int k0 = 0; k0 < K; k0 += 32) {
    async_load16(ap + k0, as);
    async_load16(bp + k0, bs);
    __syncthreads();
    bf16x8 af[2], bfr[2];
#pragma unroll
    for (int mt = 0; mt < 2; mt++)
      af[mt] = *(const bf16x8*)&As[(wm + mt * 16 + m16) * 32 + quad * 8];
#pragma unroll
    for (int nt = 0; nt < 2; nt++)
      bfr[nt] = *(const bf16x8*)&Bs[(wn + nt * 16 + m16) * 32 + quad * 8];
#pragma unroll
    for (int mt = 0; mt < 2; mt++)
#pragma unroll
      for (int nt = 0; nt < 2; nt++)
        acc[mt][nt] = __builtin_amdgcn_mfma_f32_16x16x32_bf16(af[mt], bfr[nt], acc[mt][nt], 0, 0, 0);
    __syncthreads();
  }

#pragma unroll
  for (int mt = 0; mt < 2; mt++) {
#pragma unroll
    for (int nt = 0; nt < 2; nt++) {
      int col = bn + wn + nt * 16 + m16;
      float bv = bias[col];
#pragma unroll
      for (int r = 0; r < 4; r++) {
        int row = bm + wm + mt * 16 + quad * 4 + r;
        C[(size_t)row * 1024 + col] = acc[mt][nt][r] + bv;
      }
    }
  }
}

// ---------------- gather: d_out[b,n,:] = outc[b*512+fidx(n),:], float4 stream ----------------
__global__ __launch_bounds__(256) void gather_out_kernel(
    const float* __restrict__ outc, float* __restrict__ out) {
  const int row = blockIdx.x;            // b*4096 + n
  const int b = row >> 12, n = row & (NPOS - 1);
  const int g = fidx_of(n);
  const float4* src = (const float4*)(outc + ((size_t)(b * GSZ) + g) * DIM);
  float4* dst = (float4*)(out + (size_t)row * DIM);
  dst[threadIdx.x] = src[threadIdx.x];
}

// ---------------- field: segment-sum of v * ||k|| into G bins (r9, FROZEN) ----------------
__global__ __launch_bounds__(256) void wv_field_kernel(
    const __hip_bfloat16* __restrict__ KV, float* __restrict__ field) {
  const int b = blockIdx.x, g = blockIdx.y;
  int i0, i1;
  bin_range(g, i0, i1);
  int cnt = i1 - i0;                 // 1, 8 or 9
  if (cnt > 9) cnt = 9;
  __shared__ float km[9][16];        // [row][head]
  const int tid = threadIdx.x;
  if (tid < 144) {                   // phase 1: ||k|| per (row, head); zero-fill r>=cnt
    int r = tid >> 4, h = tid & 15;
    float s = 0.f;
    if (r < cnt) {
      const unsigned short* kp = (const unsigned short*)KV + (size_t)(b * NPOS + i0 + r) * 2048 + h * 64;
#pragma unroll
      for (int e = 0; e < 64; e += 8) {
        bf16x8 v = *(const bf16x8*)(kp + e);
#pragma unroll
        for (int q = 0; q < 8; ++q) { float f = bf2f((unsigned short)v[q]); s += f * f; }
      }
      s = sqrtf(s);
    }
    km[r][h] = s;                    // 0 for padding rows
  }
  __syncthreads();
  const int c0 = tid * 4, h = tid >> 4;   // h = c0>>6
  const unsigned short* vbase = (const unsigned short*)KV + (size_t)(b * NPOS + i0) * 2048 + 1024 + c0;
  ushort4 vv[8];
  float ww[8];
#pragma unroll
  for (int j = 0; j < 8; ++j) {
    int jc = (j < cnt) ? j : 0;           // clamp: valid row, weight 0 below
    vv[j] = *(const ushort4*)(vbase + (size_t)jc * 2048);
    ww[j] = (j < cnt) ? km[j][h] : 0.f;
  }
  float a0 = 0.f, a1 = 0.f, a2 = 0.f, a3 = 0.f;
#pragma unroll
  for (int j = 0; j < 8; ++j) {
    a0 += ww[j] * bf2f(vv[j].x); a1 += ww[j] * bf2f(vv[j].y);
    a2 += ww[j] * bf2f(vv[j].z); a3 += ww[j] * bf2f(vv[j].w);
  }
  if (cnt == 9) {
    ushort4 v8 = *(const ushort4*)(vbase + (size_t)8 * 2048);
    float w8 = km[8][h];
    a0 += w8 * bf2f(v8.x); a1 += w8 * bf2f(v8.y);
    a2 += w8 * bf2f(v8.z); a3 += w8 * bf2f(v8.w);
  }
  *(float4*)(field + ((size_t)(b * GSZ + g)) * DIM + c0) = make_float4(a0, a1, a2, a3);
}

// ---------------- causal conv as EMA recurrence, LDS-staged (r9, FROZEN) ----------------
__global__ __launch_bounds__(256) void conv_ema_kernel(
    const float* __restrict__ field, __hip_bfloat16* __restrict__ convb) {
  const int b = blockIdx.x, h = blockIdx.y, n0 = blockIdx.z * 64;
  __shared__ float slab[128 * 64];
  const int tid = threadIdx.x;
  const float* fb = field + (size_t)b * GSZ * DIM + h * 64;
  for (int i = tid; i < 128 * 16; i += 256) {         // float4 loads, 8/thread
    int row = i >> 4, c4 = i & 15;
    int gg = (n0 + 257 + row) & (GSZ - 1);
    *(float4*)&slab[row * 64 + c4 * 4] = *(const float4*)(fb + (size_t)gg * DIM + c4 * 4);
  }
  __syncthreads();
  const float a = 0.71653131057378927f;   // exp(-1/3)
  const float w1 = 1.0f - a;
  const int c = tid & 63, sub = tid >> 6;
  const int e0 = sub * 16;                // emit slab range [e0, e0+16)
  float acc = 0.f;
#pragma unroll 4
  for (int t = e0 + 79; t >= e0 + 16; --t)            // 64-step warm-up (a^64 ~ 5e-10)
    acc = w1 * slab[t * 64 + c] + a * acc;
#pragma unroll
  for (int t = e0 + 15; t >= e0; --t) {
    acc = w1 * slab[t * 64 + c] + a * acc;
    convb[((size_t)(b * GSZ) + n0 + t) * DIM + h * 64 + c] = __float2bfloat16(acc);
  }
}

extern "C" void kernel_launch(void* const* d_in, const int* in_sizes, int n_in,
                              void* d_out, int out_size, void* d_ws, size_t ws_size,
                              hipStream_t stream) {
  (void)in_sizes; (void)n_in; (void)out_size; (void)ws_size;
  const float* x     = (const float*)d_in[0];
  // d_in[1]=q_w, d_in[2]=q_b: dead in the reference — skipped.
  const float* k_w   = (const float*)d_in[3];
  const float* k_b   = (const float*)d_in[4];
  const float* v_w   = (const float*)d_in[5];
  const float* v_b   = (const float*)d_in[6];
  const float* out_w = (const float*)d_in[7];
  const float* out_b = (const float*)d_in[8];

  char* p = (char*)d_ws;
  __hip_bfloat16* xb    = (__hip_bfloat16*)p;                                 // 32 MB (dead after gemm_bt)
  float*          outc  = (float*)p;          p += (size_t)16384 * 1024 * 2;  // aliases xb: 8 MB
  __hip_bfloat16* kvwb  = (__hip_bfloat16*)p; p += (size_t)2048 * 1024 * 2;   // 4 MB
  __hip_bfloat16* outwb = (__hip_bfloat16*)p; p += (size_t)1024 * 1024 * 2;   // 2 MB
  __hip_bfloat16* KV    = (__hip_bfloat16*)p; p += (size_t)16384 * 2048 * 2;  // 64 MB
  float*          field = (float*)p;          p += (size_t)4 * 512 * 1024 * 4;// 8 MB
  __hip_bfloat16* convb = (__hip_bfloat16*)p;                                 // 4 MB

  cast_all<<<19456, 256, 0, stream>>>(x, k_w, v_w, out_w, xb, kvwb, outwb);

  // fused K+V projection: (16384x1024) @ (2048x1024)^T -> KV bf16, BK=64
  gemm_bt<<<dim3(128, 16), 256, 0, stream>>>(xb, kvwb, k_b, v_b, KV, 2048);

  wv_field_kernel<<<dim3(4, 512), 256, 0, stream>>>(KV, field);
  conv_ema_kernel<<<dim3(4, 16, 8), 256, 0, stream>>>(field, convb);

  // dedup'd output GEMM (2048 distinct rows, 512 blocks) then streaming gather
  gemm_outc<<<dim3(32, 16), 256, 0, stream>>>(convb, outwb, out_b, outc);
  gather_out_kernel<<<16384, 256, 0, stream>>>(outc, (float*)d_out);
}